// Round 1
// 254.952 us; speedup vs baseline: 1.1378x; 1.1378x over previous
//
#include <hip/hip_runtime.h>
#include <cstdint>

// Fully-fused GRU: B=2048, T=256, F=64, H=32. fp32 in/out. ONE kernel.
// 512 blocks x 128 thr = 2 waves/block, wave-specialized:
//   wave 1 (producer): ring x-loads, hi/lo bf16 split, 24 x-proj MFMAs/group,
//     writes LDS (double-buffered 12KB), one group ahead of the chain.
//   wave 0 (chain): pure recurrence — per step: 6 hh MFMAs (A=W_hh K-permuted,
//     B=h bf16, C-init = folded biases), zero-redundancy acts (lane owns dims
//     (q*4+u, +16) of batch bq), h exchange via 1 pack + 4 shuffles, head fused.
//   One __syncthreads per 4-step group; chain reads buf[g&1], producer writes
//   buf[(g+1)&1] — disjoint per phase.

#define TSEQ 256

typedef __attribute__((ext_vector_type(8))) short bf16x8;
typedef __attribute__((ext_vector_type(4))) float f32x4;
union BF8 { unsigned u[4]; bf16x8 v; };

__device__ __forceinline__ unsigned bfr(float f) {            // bf16 RNE in hi16
    unsigned u = __float_as_uint(f);
    return u + 0x7fffu + ((u >> 16) & 1u);
}
__device__ __forceinline__ unsigned packhi(unsigned a, unsigned b) {
    return __builtin_amdgcn_perm(b, a, 0x07060302u);          // hi16(a)|hi16(b)<<16
}
// 8 fp32 -> hi (truncated bf16) + lo (bf16 of residual): 3-term-quality products
__device__ __forceinline__ void cvt2(const float4& f0, const float4& f1,
                                     bf16x8& hi, bf16x8& lo) {
    float f[8] = {f0.x,f0.y,f0.z,f0.w, f1.x,f1.y,f1.z,f1.w};
    BF8 H, L;
    #pragma unroll
    for (int d = 0; d < 4; ++d) {
        float a = f[2*d], b = f[2*d+1];
        unsigned ua = __float_as_uint(a), ub = __float_as_uint(b);
        float ra = a - __uint_as_float(ua & 0xffff0000u);
        float rb = b - __uint_as_float(ub & 0xffff0000u);
        H.u[d] = packhi(ua, ub);
        L.u[d] = packhi(bfr(ra), bfr(rb));
    }
    hi = H.v; lo = L.v;
}
__device__ __forceinline__ float sel4(f32x4 v, int u) {
    float a = (u & 1) ? v[1] : v[0];
    float b = (u & 1) ? v[3] : v[2];
    return (u & 2) ? b : a;
}
__device__ __forceinline__ float sigx(float v) {
    return __builtin_amdgcn_rcpf(1.f + exp2f(-1.4426950408889634f * v));
}
__device__ __forceinline__ float tanhx(float v) {
    float e = exp2f(-2.8853900817779268f * fabsf(v));
    return copysignf((1.f - e) * __builtin_amdgcn_rcpf(1.f + e), v);
}

#define MFMA16(A, B, C) __builtin_amdgcn_mfma_f32_16x16x32_bf16((A), (B), (C), 0, 0, 0)

__global__ __launch_bounds__(128, 1)
void gru_fused(const float* __restrict__ x, const float* __restrict__ W_ih,
               const float* __restrict__ W_hh, const float* __restrict__ b_ih,
               const float* __restrict__ b_hh, const float* __restrict__ W_head,
               const float* __restrict__ b_head, float* __restrict__ out)
{
    __shared__ float xsh[2][1536];                 // [buf][prod_lane*24 + nt*4 + reg]
    const int tid  = threadIdx.x;
    const int wid  = tid >> 6;                     // 0 = chain wave, 1 = producer
    const int lane = tid & 63;
    const int m = lane & 15, q = lane >> 4;
    const int bq = m & 3, u = m >> 2;              // batch-in-wave, step/dim-shard
    const int b0 = blockIdx.x * 4;

    // ===================== producer persistent state =====================
    bf16x8 Aih[6][2];
    float4 ring[4];
    const float* xcol = x + ((size_t)(b0 + bq)*TSEQ + u)*64 + q*8;
    auto ldring = [&](int grp) {
        const float* p = xcol + grp*256;           // grp*4 steps * 64 floats
        ring[0] = ((const float4*)p)[0];        ring[1] = ((const float4*)p)[1];
        ring[2] = ((const float4*)(p+32))[0];   ring[3] = ((const float4*)(p+32))[1];
    };
    auto projwrite = [&](int buf) {                // ring -> x-proj -> LDS[buf]
        bf16x8 Xh0, Xl0, Xh1, Xl1;
        cvt2(ring[0], ring[1], Xh0, Xl0);
        cvt2(ring[2], ring[3], Xh1, Xl1);
        #pragma unroll
        for (int nt = 0; nt < 6; ++nt) {
            f32x4 a = MFMA16(Aih[nt][0], Xh0, ((f32x4){0.f,0.f,0.f,0.f}));
            a = MFMA16(Aih[nt][0], Xl0, a);
            a = MFMA16(Aih[nt][1], Xh1, a);
            a = MFMA16(Aih[nt][1], Xl1, a);
            *(f32x4*)&xsh[buf][lane*24 + nt*4] = a;
        }
    };

    // ===================== chain persistent state =====================
    bf16x8 Awh[6];
    f32x4 FRZ[4], BN0, BN1;
    float fn0 = 0.f, fn1 = 0.f;
    unsigned Hd[4] = {0u, 0u, 0u, 0u};             // h B-frag dwords (bf16 pairs)
    float hOL = 0.f, hOH = 0.f;                    // own h dims (q*4+u, +16), fp32

    if (wid == 1) {
        // ---- W_ih A-frags (plain bf16): A[m][c*32+q*8+j] = W_ih[nt*16+m][...]
        #pragma unroll
        for (int nt = 0; nt < 6; ++nt)
            #pragma unroll
            for (int c = 0; c < 2; ++c) {
                const float* wp = W_ih + (nt*16 + m)*64 + c*32 + q*8;
                BF8 t;
                #pragma unroll
                for (int d = 0; d < 4; ++d) t.u[d] = packhi(bfr(wp[2*d]), bfr(wp[2*d+1]));
                Aih[nt][c] = t.v;
            }
        ldring(0);
        projwrite(0);                              // group-0 data into buf 0
        ldring(1);
    } else {
        // ---- W_hh A-frags, K-permuted: pos p=q*8+j <-> dim (p>>1)+16*(p&1)
        #pragma unroll
        for (int nt = 0; nt < 6; ++nt) {
            const float* wp = W_hh + (nt*16 + m)*32;
            BF8 t;
            #pragma unroll
            for (int d = 0; d < 4; ++d) {
                int dd = q*4 + d;
                t.u[d] = packhi(bfr(wp[dd]), bfr(wp[dd + 16]));
            }
            Awh[nt] = t.v;
        }
        // ---- biases: C-init vectors (component reg <-> gate nt*16+q*4+reg)
        #pragma unroll
        for (int nt = 0; nt < 4; ++nt) {
            f32x4 t;
            #pragma unroll
            for (int r = 0; r < 4; ++r) { int g = nt*16 + q*4 + r; t[r] = b_ih[g] + b_hh[g]; }
            FRZ[nt] = t;
        }
        #pragma unroll
        for (int r = 0; r < 4; ++r) { BN0[r] = b_hh[64+q*4+r]; BN1[r] = b_hh[80+q*4+r]; }
        fn0 = b_ih[64 + q*4 + u]; fn1 = b_ih[80 + q*4 + u];
    }
    __syncthreads();                               // buf0 ready

    const int s0 = (q << 4) + bq;                  // h-exchange source base lane
    for (int g = 0; g < 64; ++g) {
        if (wid == 1) {
            // producer: stage group g+1 into buf[(g+1)&1] (chain is in buf[g&1])
            if (g < 63) {
                projwrite((g + 1) & 1);
                ldring(g + 2 < 64 ? g + 2 : 63);
            }
        } else {
            // chain: this group's x-pre scalars (24 ds_read_b32, off-chain)
            const int cbuf = g & 1;
            float xp[4][6];
            #pragma unroll
            for (int s = 0; s < 4; ++s) {
                const float* rp = &xsh[cbuf][(s0 + 4*s)*24 + u];
                #pragma unroll
                for (int nt = 0; nt < 6; ++nt) xp[s][nt] = rp[nt*4];
            }
            #pragma unroll
            for (int s = 0; s < 4; ++s) {
                BF8 bh; bh.u[0]=Hd[0]; bh.u[1]=Hd[1]; bh.u[2]=Hd[2]; bh.u[3]=Hd[3];
                f32x4 a0 = MFMA16(Awh[0], bh.v, FRZ[0]);
                f32x4 a1 = MFMA16(Awh[1], bh.v, FRZ[1]);
                f32x4 a2 = MFMA16(Awh[2], bh.v, FRZ[2]);
                f32x4 a3 = MFMA16(Awh[3], bh.v, FRZ[3]);
                f32x4 a4 = MFMA16(Awh[4], bh.v, BN0);
                f32x4 a5 = MFMA16(Awh[5], bh.v, BN1);

                float r0 = sigx(xp[s][0] + sel4(a0, u));
                float r1 = sigx(xp[s][1] + sel4(a1, u));
                float z0 = sigx(xp[s][2] + sel4(a2, u));
                float z1 = sigx(xp[s][3] + sel4(a3, u));
                float t0 = tanhx(xp[s][4] + fn0 + r0 * sel4(a4, u));
                float t1 = tanhx(xp[s][5] + fn1 + r1 * sel4(a5, u));
                float hNL = t0 + z0 * (hOL - t0);
                float hNH = t1 + z1 * (hOH - t1);
                hOL = hNL; hOH = hNH;

                // rebuild B-frag: pack own (hL,hH) once, then 4 shuffles.
                // Hd[w] = pk of lane (16q + bq + 4w): dims (q*4+w, +16) of batch bq
                unsigned pk = packhi(bfr(hNL), bfr(hNH));
                #pragma unroll
                for (int w = 0; w < 4; ++w)
                    Hd[w] = (unsigned)__shfl((int)pk, s0 + (w << 2), 64);
            }
        }
        __syncthreads();
    }

    // ---- head: chain lane holds fp32 h dims (q*4+u, +16) of batch bq
    if (wid == 0) {
        float v = hOL * W_head[q*4 + u] + hOH * W_head[16 + q*4 + u];
        v += __shfl_xor(v, 4, 64);
        v += __shfl_xor(v, 8, 64);
        v += __shfl_xor(v, 16, 64);
        v += __shfl_xor(v, 32, 64);
        if (lane < 4) out[b0 + lane] = sigx(v + b_head[0]);
    }
}

extern "C" void kernel_launch(void* const* d_in, const int* in_sizes, int n_in,
                              void* d_out, int out_size, void* d_ws, size_t ws_size,
                              hipStream_t stream)
{
    const float* x      = (const float*)d_in[0];
    const float* W_ih   = (const float*)d_in[1];
    const float* W_hh   = (const float*)d_in[2];
    const float* b_ih   = (const float*)d_in[3];
    const float* b_hh   = (const float*)d_in[4];
    const float* W_head = (const float*)d_in[5];
    const float* b_head = (const float*)d_in[6];
    float* out = (float*)d_out;

    gru_fused<<<512, 128, 0, stream>>>(x, W_ih, W_hh, b_ih, b_hh,
                                       W_head, b_head, out);
}